// Round 7
// baseline (254.234 us; speedup 1.0000x reference)
//
#include <hip/hip_runtime.h>
#include <stdint.h>

typedef float f32x4 __attribute__((ext_vector_type(4)));
typedef __bf16 bf16x8 __attribute__((ext_vector_type(8)));
typedef unsigned short u16;
typedef u16 u16x8 __attribute__((ext_vector_type(8)));

__device__ __forceinline__ u16 f2bf(float f) {
  uint32_t u = __builtin_bit_cast(uint32_t, f);
  return (u16)((u + 0x7fffu + ((u >> 16) & 1u)) >> 16);
}
__device__ __forceinline__ float bf2f(u16 h) {
  uint32_t u = ((uint32_t)h) << 16;
  return __builtin_bit_cast(float, u);
}
__device__ __forceinline__ float elup1(float x) {
  return x > 0.f ? x + 1.f : __expf(x);
}
__device__ __forceinline__ void gll16(const void* g, void* l) {
  __builtin_amdgcn_global_load_lds(
      (const __attribute__((address_space(1))) unsigned int*)g,
      (__attribute__((address_space(3))) unsigned int*)l, 16, 0, 0);
}

#define BAR() __builtin_amdgcn_s_barrier()
#define LGKM0() asm volatile("s_waitcnt lgkmcnt(0)" ::: "memory")
#define SCHED0() __builtin_amdgcn_sched_barrier(0)
#define VMC(n) asm volatile("s_waitcnt vmcnt(" #n ")" ::: "memory")

// ---------------- fused f32 -> bf16 conversion (all 3 tensors) -----------
__global__ void cvt_all_kernel(const float* __restrict__ x, u16* __restrict__ xb,
                               const float* __restrict__ wq, u16* __restrict__ wqb,
                               const float* __restrict__ wo, u16* __restrict__ wob) {
  int i = blockIdx.x * 256 + threadIdx.x;  // float4 index, 5242880 total
  const float* in;
  u16* out;
  if (i < 4194304) {
    in = x; out = xb;
  } else if (i < 4980736) {
    in = wq; out = wqb; i -= 4194304;
  } else {
    in = wo; out = wob; i -= 4980736;
  }
  float4 f = ((const float4*)in)[i];
  ushort4 o;
  o.x = f2bf(f.x); o.y = f2bf(f.y); o.z = f2bf(f.z); o.w = f2bf(f.w);
  ((ushort4*)out)[i] = o;
}

// ============ 128x128 bf16 GEMM  C[M,N] = A[M,K]*B[N,K]^T =================
// 256 threads (4 waves, 2M x 2N; wave tile 64x64). BK=64. LDS 64 KiB
// (2 dbuf x (A 16K + B 16K)) -> 2 BLOCKS PER CU: the 2 waves sharing each
// SIMD belong to different barrier domains, so HW wave scheduling hides
// barrier/vmcnt drains across blocks (the m97 TLP mechanism).
// 3-deep half-tile pipeline per K-tile t (buf d = t&1):
//   READ_ALL(d) -> lgkm0+sched0 -> BAR(MID)        // frags reg-resident
//   STAGE_ALL(t+2 -> d)                            // overwrite d, safe
//   MFMA x32 (setprio)
//   VMC: keep t+2 in flight, force t+1 landed -> BAR(END)
// Swizzle: stored colbyte = logical colbyte ^ ((row&7)<<4); gll dest linear,
// source pre-swizzled (rule #21).
// EPI==0: qkv epilogue (bias + elu+1 on cols<2048, bf16 store, LDS-coalesced)
// EPI==1: out epilogue (bias, f32 store — already line-coalesced)
template <int EPI>
__global__ __launch_bounds__(256, 2)
void gemm128(const u16* __restrict__ A, const u16* __restrict__ B,
             const float* __restrict__ bias, void* __restrict__ Cout,
             int N, int K, int nbj) {
  __shared__ __align__(16) u16 lds[32768];  // 64 KiB
  const int tid = threadIdx.x;
  const int wave = tid >> 6, lane = tid & 63;
  const int fr = lane & 15, fq = lane >> 4;
  const int wm = wave >> 1, wn = wave & 1;

  // XCD-aware bijective block swizzle (grid % 8 == 0 by construction)
  const int nwg = gridDim.x;
  const int cpx = nwg >> 3;
  const int swz = (blockIdx.x & 7) * cpx + (blockIdx.x >> 3);
  const int bi = swz / nbj, bj = swz % nbj;

  const u16* Ab = A + (size_t)bi * 128 * K;
  const u16* Bb = B + (size_t)bj * 128 * K;

  // staging: inst i covers rows i*32..i*32+31; thread t -> row i*32+(t>>3),
  // fetches global colbyte ((t&7)^((t>>3)&7))*16, lands at linear colbyte (t&7)*16
  const int cswz = ((tid & 7) ^ ((tid >> 3) & 7)) << 3;  // elements
  const int srow = tid >> 3;                             // 0..31

#define STAGE_ALL(d, k0)                                                       \
  { _Pragma("unroll")                                                          \
    for (int i_ = 0; i_ < 4; ++i_)                                             \
      gll16(Ab + (size_t)(i_ * 32 + srow) * K + (k0) + cswz,                   \
            &lds[((d) * 32768 + i_ * 4096 + wave * 1024) >> 1]);               \
    _Pragma("unroll")                                                          \
    for (int i_ = 0; i_ < 4; ++i_)                                             \
      gll16(Bb + (size_t)(i_ * 32 + srow) * K + (k0) + cswz,                   \
            &lds[((d) * 32768 + 16384 + i_ * 4096 + wave * 1024) >> 1]);       \
  }

  // fragment-read addressing (bytes)
  const int xorc = (fr & 7) << 4;
  const int acol[2] = {(fq * 16) ^ xorc, (64 + fq * 16) ^ xorc};
  const int arow = (wm * 64 + fr) * 128;  // + mm*2048
  const int brow = (wn * 64 + fr) * 128;  // + nn*2048

#define LDSV(off) (*(const bf16x8*)&lds[(off) >> 1])

  f32x4 acc[4][4] = {};
  bf16x8 af[4][2], bf[4][2];

#define READ_ALL(d)                                                            \
  { _Pragma("unroll")                                                          \
    for (int ks = 0; ks < 2; ++ks) {                                           \
      _Pragma("unroll")                                                        \
      for (int nn = 0; nn < 4; ++nn)                                           \
        bf[nn][ks] = LDSV((d) * 32768 + 16384 + brow + nn * 2048 + acol[ks]);  \
      _Pragma("unroll")                                                        \
      for (int mm = 0; mm < 4; ++mm)                                           \
        af[mm][ks] = LDSV((d) * 32768 + arow + mm * 2048 + acol[ks]);          \
    } }

#define MFMA_ALL()                                                             \
  { __builtin_amdgcn_s_setprio(1);                                             \
    _Pragma("unroll")                                                          \
    for (int ks = 0; ks < 2; ++ks) {                                           \
      _Pragma("unroll")                                                        \
      for (int mm = 0; mm < 4; ++mm) {                                         \
        _Pragma("unroll")                                                      \
        for (int nn = 0; nn < 4; ++nn)                                         \
          acc[mm][nn] = __builtin_amdgcn_mfma_f32_16x16x32_bf16(               \
              af[mm][ks], bf[nn][ks], acc[mm][nn], 0, 0, 0);                   \
      } }                                                                      \
    __builtin_amdgcn_s_setprio(0); }

  const int NT = K >> 6;
  // prologue: stage t0 and t1 (8 gll each); force t0 landed, t1 in flight
  STAGE_ALL(0, 0);
  STAGE_ALL(1, 64);
  VMC(8);
  BAR();

  for (int t = 0; t < NT; ++t) {
    const int d = t & 1;
    READ_ALL(d);
    LGKM0(); SCHED0();   // all frags register-resident
    BAR();               // MID: every wave's reads of buf d serviced
    if (t + 2 < NT) STAGE_ALL(d, (t + 2) << 6);
    MFMA_ALL();
    if (t + 2 < NT) { VMC(8); }        // force t+1's 8, keep t+2's 8 in flight
    else if (t + 1 < NT) { VMC(0); }   // last prefetch: drain
    BAR();               // END: buf d^1 (tile t+1) fully landed
  }

  // ---- epilogue
  const int wrow = wm * 64, wcol = wn * 64;
  if (EPI == 0) {
    const bool do_elu = (bj * 128) < 2048;  // 2048 is 128-aligned
    float bv[4];
#pragma unroll
    for (int n = 0; n < 4; ++n) bv[n] = bias[bj * 128 + wcol + n * 16 + fr];
    u16* wbuf = &lds[wave * 2048];  // wave-private 4 KiB
    const int lrow = lane >> 3, lcol = (lane & 7) * 8;
#pragma unroll
    for (int mm = 0; mm < 4; ++mm) {
#pragma unroll
      for (int n = 0; n < 4; ++n)
#pragma unroll
        for (int r = 0; r < 4; ++r) {
          float v = acc[mm][n][r] + bv[n];
          if (do_elu) v = elup1(v);
          wbuf[(fq * 4 + r) * 72 + n * 16 + fr] = f2bf(v);
        }
      // per-wave LDS ops are in-order: cross-lane read-back safe sans barrier
#pragma unroll
      for (int i = 0; i < 2; ++i) {
        bf16x8 val = *(const bf16x8*)&wbuf[(i * 8 + lrow) * 72 + lcol];
        const int rowg = bi * 128 + wrow + mm * 16 + i * 8 + lrow;
        *(bf16x8*)&((u16*)Cout)[(size_t)rowg * N + bj * 128 + wcol + lcol] = val;
      }
    }
  } else {
#pragma unroll
    for (int n = 0; n < 4; ++n) {
      const int colg = bj * 128 + wcol + n * 16 + fr;
      const float bv = bias[colg];
#pragma unroll
      for (int mm = 0; mm < 4; ++mm)
#pragma unroll
        for (int r = 0; r < 4; ++r) {
          const int rowg = bi * 128 + wrow + mm * 16 + fq * 4 + r;
          ((float*)Cout)[(size_t)rowg * N + colg] = acc[mm][n][r] + bv;
        }
    }
  }
#undef STAGE_ALL
#undef READ_ALL
#undef MFMA_ALL
#undef LDSV
}

// ---------------- kv state partials: kv[d][e] = sum_s k[s,d]*v[s,e] -------
// grid: (64 bh, 8 s-chunks of 512); block 256 = 4 s-slices x (8d x 8e) grps.
// Per thread: 8x8 register tile (64 FMA per 64 LDS-bytes), cross-slice
// reduction via LDS at block end (deterministic).
__global__ __launch_bounds__(256)
void kv_state_kernel(const u16* __restrict__ qkv, float* __restrict__ pkv,
                     float* __restrict__ pks) {
  const int bh = blockIdx.x, chunk = blockIdx.y;
  const int b = bh >> 4, h = bh & 15;
  const int t = threadIdx.x;
  __shared__ float smem[16416];  // staging 2176 floats; reduce 16384+32
  float (*sK)[68] = (float(*)[68])smem;
  float (*sV)[68] = (float(*)[68])(smem + 1088);
  const int s4 = t >> 6;             // s-slice 0-3
  const int dq = (t >> 3) & 7;       // d-group
  const int eq = t & 7;              // e-group
  const int d8 = dq * 8, e8 = eq * 8;
  f32x4 accA[8] = {}, accB[8] = {};  // [di] x (e8..+3, e8+4..+7)
  float ak[8] = {};
  const size_t rowbase = ((size_t)b * 4096 + (size_t)chunk * 512) * 3072;
  const u16* kp = qkv + rowbase + 1024 + h * 64;
  const u16* vp = qkv + rowbase + 2048 + h * 64;
  // staging: 128 threads K, 128 threads V; 16B/lane
  const int lhalf = t >> 7, lr = (t >> 3) & 15, lc = (t & 7) * 8;
  const u16* lsrc = lhalf ? vp : kp;
  float* ldst = lhalf ? &sV[lr][lc] : &sK[lr][lc];
  for (int s0 = 0; s0 < 512; s0 += 16) {
    u16x8 v8 = *(const u16x8*)&lsrc[(size_t)(s0 + lr) * 3072 + lc];
#pragma unroll
    for (int j = 0; j < 8; ++j) ldst[j] = bf2f(v8[j]);
    __syncthreads();
#pragma unroll
    for (int j = 0; j < 4; ++j) {
      const int sl = j * 4 + s4;
      f32x4 ka = *(const f32x4*)&sK[sl][d8];
      f32x4 kb = *(const f32x4*)&sK[sl][d8 + 4];
      f32x4 va = *(const f32x4*)&sV[sl][e8];
      f32x4 vb = *(const f32x4*)&sV[sl][e8 + 4];
#pragma unroll
      for (int di = 0; di < 4; ++di) {
        accA[di] += ka[di] * va;
        accB[di] += ka[di] * vb;
        accA[4 + di] += kb[di] * va;
        accB[4 + di] += kb[di] * vb;
      }
      if (eq == 0) {
#pragma unroll
        for (int di = 0; di < 4; ++di) {
          ak[di] += ka[di];
          ak[4 + di] += kb[di];
        }
      }
    }
    __syncthreads();
  }
  // cross-slice reduction (8 passes, deterministic order)
  float* red = smem;
  float* redk = smem + 16384;
  float* outp = pkv + ((size_t)chunk * 64 + bh) * 4096;
  float* outk = pks + ((size_t)chunk * 64 + bh) * 64;
  for (int di = 0; di < 8; ++di) {
    __syncthreads();
    *(f32x4*)&red[t * 8] = accA[di];
    *(f32x4*)&red[t * 8 + 4] = accB[di];
    if (eq == 0) redk[s4 * 8 + dq] = ak[di];
    __syncthreads();
    if (t < 64) {
      const int rdq = t >> 3, req = t & 7;
      f32x4 sA = {}, sB = {};
#pragma unroll
      for (int s = 0; s < 4; ++s) {
        const int src = (s * 64 + rdq * 8 + req) * 8;
        sA += *(const f32x4*)&red[src];
        sB += *(const f32x4*)&red[src + 4];
      }
      float* op = outp + (rdq * 8 + di) * 64 + req * 8;
      *(f32x4*)op = sA;
      *(f32x4*)(op + 4) = sB;
      if (req == 0)
        outk[rdq * 8 + di] = redk[rdq] + redk[8 + rdq] + redk[16 + rdq] + redk[24 + rdq];
    }
  }
}

// ---------------- reduce partials, fold division --------------------------
__global__ __launch_bounds__(256)
void kv_reduce_kernel(const float* __restrict__ pkv, const float* __restrict__ pks,
                      float* __restrict__ kvn) {
  const int bh = blockIdx.x;
  const int t = threadIdx.x;
  __shared__ float sks[64];
  if (t < 64) {
    float s = 0.f;
    for (int c = 0; c < 8; ++c) s += pks[((size_t)c * 64 + bh) * 64 + t];
    sks[t] = s + 1e-6f;
  }
  __syncthreads();
#pragma unroll
  for (int j = 0; j < 16; ++j) {
    int idx = t + j * 256;
    float s = 0.f;
    for (int c = 0; c < 8; ++c) s += pkv[((size_t)c * 64 + bh) * 4096 + idx];
    kvn[(size_t)bh * 4096 + idx] = s / sks[idx & 63];
  }
}

// ---------------- attn out: o[s,e] = sum_d q[s,d]*kvn[d,e] via MFMA -------
// grid: (64 bh, 64 s-tiles of 64 rows); block 256 (4 waves x 16 rows)
__global__ __launch_bounds__(256)
void attn_out_kernel(const u16* __restrict__ qkv, const float* __restrict__ kvn,
                     u16* __restrict__ attn) {
  const int bh = blockIdx.x;
  const int b = bh >> 4, h = bh & 15;
  const int stile = blockIdx.y;
  const int wave = threadIdx.x >> 6, lane = threadIdx.x & 63;
  const int s0 = stile * 64 + wave * 16;
  const int fr = lane & 15, fq = lane >> 4;
  __shared__ u16 sO[4][16 * 72];
  const float* kv = kvn + (size_t)bh * 4096;
  bf16x8 bfrag[2][4];
#pragma unroll
  for (int ks = 0; ks < 2; ++ks)
#pragma unroll
    for (int n = 0; n < 4; ++n) {
      u16x8 tmp;
#pragma unroll
      for (int j = 0; j < 8; ++j)
        tmp[j] = f2bf(kv[(size_t)(ks * 32 + fq * 8 + j) * 64 + n * 16 + fr]);
      bfrag[ks][n] = __builtin_bit_cast(bf16x8, tmp);
    }
  const u16* q = qkv + (size_t)b * 4096 * 3072 + h * 64;
  f32x4 acc[4] = {};
#pragma unroll
  for (int ks = 0; ks < 2; ++ks) {
    bf16x8 af = *(const bf16x8*)&q[(size_t)(s0 + fr) * 3072 + ks * 32 + fq * 8];
#pragma unroll
    for (int n = 0; n < 4; ++n)
      acc[n] = __builtin_amdgcn_mfma_f32_16x16x32_bf16(af, bfrag[ks][n], acc[n], 0, 0, 0);
  }
  u16* wb = &sO[wave][0];
#pragma unroll
  for (int n = 0; n < 4; ++n)
#pragma unroll
    for (int r = 0; r < 4; ++r)
      wb[(fq * 4 + r) * 72 + n * 16 + fr] = f2bf(acc[n][r]);
  u16* ap = attn + (size_t)b * 4096 * 1024 + h * 64;
  const int lrow = lane >> 3, lcol = (lane & 7) * 8;
#pragma unroll
  for (int i = 0; i < 2; ++i) {
    bf16x8 val = *(const bf16x8*)&wb[(i * 8 + lrow) * 72 + lcol];
    *(bf16x8*)&ap[(size_t)(s0 + i * 8 + lrow) * 1024 + lcol] = val;
  }
}

// -------------------------------------------------------------------------
extern "C" void kernel_launch(void* const* d_in, const int* in_sizes, int n_in,
                              void* d_out, int out_size, void* d_ws, size_t ws_size,
                              hipStream_t stream) {
  const float* x     = (const float*)d_in[0];
  const float* w_qkv = (const float*)d_in[1];
  const float* b_qkv = (const float*)d_in[2];
  const float* w_out = (const float*)d_in[3];
  const float* b_out = (const float*)d_in[4];
  float* out = (float*)d_out;

  const int M = 16384, Dm = 1024, N3 = 3072;

  char* ws = (char*)d_ws;
  u16* xb     = (u16*)(ws);                    //  33,554,432 B
  u16* wqb    = (u16*)(ws + 33554432);         //   6,291,456 B
  u16* wob    = (u16*)(ws + 39845888);         //   2,097,152 B
  u16* qkvb   = (u16*)(ws + 41943040);         // 100,663,296 B
  u16* attnb  = (u16*)(ws + 142606336);        //  33,554,432 B
  float* pkv  = (float*)(ws + 176160768);      //   8,388,608 B
  float* pks  = (float*)(ws + 184549376);      //     131,072 B
  float* kvn  = (float*)(ws + 184680448);      //   1,048,576 B

  cvt_all_kernel<<<20480, 256, 0, stream>>>(x, xb, w_qkv, wqb, w_out, wob);

  gemm128<0><<<(M / 128) * (N3 / 128), 256, 0, stream>>>(xb, wqb, b_qkv, qkvb, N3, Dm, N3 / 128);
  kv_state_kernel<<<dim3(64, 8), 256, 0, stream>>>(qkvb, pkv, pks);
  kv_reduce_kernel<<<64, 256, 0, stream>>>(pkv, pks, kvn);
  attn_out_kernel<<<dim3(64, 64), 256, 0, stream>>>(qkvb, kvn, attnb);
  gemm128<1><<<(M / 128) * (Dm / 128), 256, 0, stream>>>(attnb, wob, b_out, out, Dm, Dm, Dm / 128);
}

// Round 8
// 224.994 us; speedup vs baseline: 1.1300x; 1.1300x over previous
//
#include <hip/hip_runtime.h>
#include <stdint.h>

typedef float f32x4 __attribute__((ext_vector_type(4)));
typedef __bf16 bf16x8 __attribute__((ext_vector_type(8)));
typedef unsigned short u16;
typedef u16 u16x8 __attribute__((ext_vector_type(8)));

__device__ __forceinline__ u16 f2bf(float f) {
  uint32_t u = __builtin_bit_cast(uint32_t, f);
  return (u16)((u + 0x7fffu + ((u >> 16) & 1u)) >> 16);
}
__device__ __forceinline__ float bf2f(u16 h) {
  uint32_t u = ((uint32_t)h) << 16;
  return __builtin_bit_cast(float, u);
}
__device__ __forceinline__ float elup1(float x) {
  return x > 0.f ? x + 1.f : __expf(x);
}
__device__ __forceinline__ void gll16(const void* g, void* l) {
  __builtin_amdgcn_global_load_lds(
      (const __attribute__((address_space(1))) unsigned int*)g,
      (__attribute__((address_space(3))) unsigned int*)l, 16, 0, 0);
}

#define BAR() __builtin_amdgcn_s_barrier()
#define VMC(n) asm volatile("s_waitcnt vmcnt(" #n ")" ::: "memory")

// ---------------- fused f32 -> bf16 conversion (all 3 tensors) -----------
__global__ void cvt_all_kernel(const float* __restrict__ x, u16* __restrict__ xb,
                               const float* __restrict__ wq, u16* __restrict__ wqb,
                               const float* __restrict__ wo, u16* __restrict__ wob) {
  int i = blockIdx.x * 256 + threadIdx.x;  // float4 index, 5242880 total
  const float* in;
  u16* out;
  if (i < 4194304) {
    in = x; out = xb;
  } else if (i < 4980736) {
    in = wq; out = wqb; i -= 4194304;
  } else {
    in = wo; out = wob; i -= 4980736;
  }
  float4 f = ((const float4*)in)[i];
  ushort4 o;
  o.x = f2bf(f.x); o.y = f2bf(f.y); o.z = f2bf(f.z); o.w = f2bf(f.w);
  ((ushort4*)out)[i] = o;
}

// ============ 256x256 bf16 GEMM  C[M,N] = A[M,K]*B[N,K]^T =================
// 512 threads (8 waves, 2M x 4N; wave tile 128x64). BK=64.
// LDS 128 KiB (2 dbuf x (A 32K + B 32K)), simple 2-deep pipeline:
// stage t+1 -> buf d^1 mid-tile; ONE vmcnt(0)+barrier per K-tile.
// BOTH A-half fragment sets live in regs (af0/af1) so no read cluster
// WAR-collides with the in-flight MFMA cluster; reads issued one cluster
// ahead (lookahead-1) so LDS service hides under MFMA issue. Waves stagger
// A-half order by parity to anti-phase the shared LDS queue.
// lda parametrized (out-proj reads q' cols of qkvb, lda=3072).
// bstep: B advances by bstep per 16 M-tiles (per-batch W2T); 0 = shared B.
// EPI==0: qkv epilogue (bias + elu+1 on cols<2048, bf16 store, LDS-coalesced)
// EPI==1: out epilogue (bias, f32 store)
template <int EPI>
__global__ __launch_bounds__(512, 2)
void gemm256(const u16* __restrict__ A, int lda, const u16* __restrict__ B,
             const float* __restrict__ bias, void* __restrict__ Cout,
             int N, int K, int nbj, int bstep) {
  __shared__ __align__(16) u16 lds[65536];  // 128 KiB
  const int tid = threadIdx.x;
  const int wave = tid >> 6, lane = tid & 63;
  const int fr = lane & 15, fq = lane >> 4;
  const int wm = wave >> 2, wn = wave & 3;

  // XCD-aware bijective block swizzle (grid % 8 == 0 by construction)
  const int nwg = gridDim.x;
  const int cpx = nwg >> 3;
  const int swz = (blockIdx.x & 7) * cpx + (blockIdx.x >> 3);
  const int bi = swz / nbj, bj = swz % nbj;

  const u16* Ab = A + (size_t)bi * 256 * lda;
  const u16* Bb = B + (size_t)(bi >> 4) * bstep + (size_t)bj * 256 * K;

  // staging geometry (verified r3-r6): per inst, thread covers LDS bytes
  // i*8192 + wave*1024 + lane*16 (linear dest; source pre-swizzled, rule #21)
  const int l8 = lane >> 3;                       // ldsrow & 7
  const int cswz = ((lane & 7) ^ l8) << 3;        // swizzled col offset (elements)
  const int r6 = wave * 8 + l8;                   // row within 64-row inst block

#define STAGE_A(d, h, k0)                                                      \
  { _Pragma("unroll")                                                          \
    for (int i_ = 0; i_ < 2; ++i_) {                                           \
      int gr_ = i_ * 128 + (h) * 64 + r6;                                      \
      gll16(Ab + (size_t)gr_ * lda + (k0) + cswz,                              \
            &lds[((d) * 32768 + (h) * 16384 + i_ * 8192 + wave * 1024) >> 1]); \
    } }

#define STAGE_B(d, h, k0)                                                      \
  { _Pragma("unroll")                                                          \
    for (int i_ = 0; i_ < 2; ++i_) {                                           \
      int r_ = i_ * 64 + r6;                                                   \
      int gr_ = (r_ >> 5) * 64 + (h) * 32 + (r_ & 31);                         \
      gll16(Bb + (size_t)gr_ * K + (k0) + cswz,                                \
            &lds[(65536 + (d) * 32768 + (h) * 16384 + i_ * 8192 + wave * 1024) >> 1]); \
    } }

#define STAGE_ALL(d, k0) \
  { STAGE_A(d, 0, k0); STAGE_A(d, 1, k0); STAGE_B(d, 0, k0); STAGE_B(d, 1, k0); }

  // fragment-read addressing (bytes)
  const int xorc = (fr & 7) << 4;
  const int acol[2] = {(fq * 16) ^ xorc, (64 + fq * 16) ^ xorc};
  const int arow = (wm * 64 + fr) * 128;
  const int brow = (wn * 32 + fr) * 128;

#define LDSV(off) (*(const bf16x8*)&lds[(off) >> 1])

  f32x4 acc[8][4] = {};
  bf16x8 af0[4][2], af1[4][2];  // BOTH A-halves live (no WAR with MFMA)
  bf16x8 bfr[2][2][2];          // B frags [nh][nn][ks], both halves live

#define READ_A(d, mh, dst)                                                     \
  { _Pragma("unroll")                                                          \
    for (int ks = 0; ks < 2; ++ks) {                                           \
      _Pragma("unroll")                                                        \
      for (int mm = 0; mm < 4; ++mm)                                           \
        dst[mm][ks] = LDSV((d) * 32768 + (mh) * 16384 + arow + mm * 2048 + acol[ks]); \
    } }

#define READ_B(d, nh)                                                          \
  { _Pragma("unroll")                                                          \
    for (int ks = 0; ks < 2; ++ks) {                                           \
      _Pragma("unroll")                                                        \
      for (int nn = 0; nn < 2; ++nn)                                           \
        bfr[nh][nn][ks] = LDSV(65536 + (d) * 32768 + (nh) * 16384 + brow + nn * 2048 + acol[ks]); \
    } }

#define MFMA_Q(mh, nh, src)                                                    \
  { __builtin_amdgcn_s_setprio(1);                                             \
    _Pragma("unroll")                                                          \
    for (int ks = 0; ks < 2; ++ks) {                                           \
      _Pragma("unroll")                                                        \
      for (int mm = 0; mm < 4; ++mm) {                                         \
        _Pragma("unroll")                                                      \
        for (int nn = 0; nn < 2; ++nn)                                         \
          acc[(mh) * 4 + mm][(nh) * 2 + nn] = __builtin_amdgcn_mfma_f32_16x16x32_bf16( \
              src[mm][ks], bfr[nh][nn][ks], acc[(mh) * 4 + mm][(nh) * 2 + nn], 0, 0, 0); \
      } }                                                                      \
    __builtin_amdgcn_s_setprio(0); }

  // F = first A-half computed, S = second; parity-staggered across waves.
#define TILE_BODY(F, S, afF, afS, d, t)                                        \
  {                                                                            \
    READ_B(d, 0); READ_B(d, 1); READ_A(d, F, afF);                             \
    MFMA_Q(F, 0, afF);                                                         \
    READ_A(d, S, afS);                                                         \
    MFMA_Q(F, 1, afF);                                                         \
    if ((t) + 1 < NT) STAGE_ALL((d) ^ 1, ((t) + 1) << 6);                      \
    MFMA_Q(S, 1, afS);                                                         \
    MFMA_Q(S, 0, afS);                                                         \
  }

  const int NT = K >> 6;
  STAGE_ALL(0, 0);
  VMC(0);
  BAR();

  if ((wave & 1) == 0) {
    for (int t = 0; t < NT; ++t) {
      const int d = t & 1;
      TILE_BODY(0, 1, af0, af1, d, t);
      VMC(0); BAR();
    }
  } else {
    for (int t = 0; t < NT; ++t) {
      const int d = t & 1;
      TILE_BODY(1, 0, af1, af0, d, t);
      VMC(0); BAR();
    }
  }

  // ---- epilogue
  const int wrow = wm * 128, wcol = wn * 64;
  if (EPI == 0) {
    const bool do_elu = (bj * 256) < 2048;  // 2048 is 256-aligned
    float bv[4];
#pragma unroll
    for (int n = 0; n < 4; ++n) bv[n] = bias[bj * 256 + wcol + n * 16 + fr];
    u16* wbuf = &lds[wave * 8192];  // wave-private 16 KiB
    const int lrow = lane >> 3, lcol = (lane & 7) * 8;
#pragma unroll
    for (int ch = 0; ch < 2; ++ch) {
#pragma unroll
      for (int m2 = 0; m2 < 4; ++m2)
#pragma unroll
        for (int n = 0; n < 4; ++n)
#pragma unroll
          for (int r = 0; r < 4; ++r) {
            float v = acc[ch * 4 + m2][n][r] + bv[n];
            if (do_elu) v = elup1(v);
            wbuf[(m2 * 16 + fq * 4 + r) * 72 + n * 16 + fr] = f2bf(v);
          }
#pragma unroll
      for (int i = 0; i < 8; ++i) {
        bf16x8 val = *(const bf16x8*)&wbuf[(i * 8 + lrow) * 72 + lcol];
        const int rowg = bi * 256 + wrow + ch * 64 + i * 8 + lrow;
        *(bf16x8*)&((u16*)Cout)[(size_t)rowg * N + bj * 256 + wcol + lcol] = val;
      }
    }
  } else {
#pragma unroll
    for (int n = 0; n < 4; ++n) {
      const int colg = bj * 256 + wcol + n * 16 + fr;
      const float bv = bias[colg];
#pragma unroll
      for (int m = 0; m < 8; ++m)
#pragma unroll
        for (int r = 0; r < 4; ++r) {
          const int rowg = bi * 256 + wrow + m * 16 + fq * 4 + r;
          ((float*)Cout)[(size_t)rowg * N + colg] = acc[m][n][r] + bv;
        }
    }
  }
#undef STAGE_A
#undef STAGE_B
#undef STAGE_ALL
#undef READ_A
#undef READ_B
#undef MFMA_Q
#undef TILE_BODY
#undef LDSV
}

// ---------------- kv state partials: kv[d][e] = sum_s k[s,d]*v[s,e] -------
// grid: (64 bh, 8 s-chunks of 512); block 256; 4d x 4e register blocking.
__global__ __launch_bounds__(256)
void kv_state_kernel(const u16* __restrict__ qkv, float* __restrict__ pkv,
                     float* __restrict__ pks) {
  const int bh = blockIdx.x, chunk = blockIdx.y;
  const int b = bh >> 4, h = bh & 15;
  const int t = threadIdx.x;
  __shared__ float sK[16][68];
  __shared__ float sV[16][68];
  const int dg = (t & 15) * 4;
  const int eg = (t >> 4) * 4;
  f32x4 acc0 = {}, acc1 = {}, acc2 = {}, acc3 = {};
  f32x4 ak4 = {};
  const size_t rowbase = ((size_t)b * 4096 + (size_t)chunk * 512) * 3072;
  const u16* kp = qkv + rowbase + 1024 + h * 64;
  const u16* vp = qkv + rowbase + 2048 + h * 64;
  const int lhalf = t >> 7, lr = (t >> 3) & 15, lc = (t & 7) * 8;
  const u16* lsrc = lhalf ? vp : kp;
  float* ldst = lhalf ? &sV[lr][lc] : &sK[lr][lc];
  for (int s0 = 0; s0 < 512; s0 += 16) {
    u16x8 v8 = *(const u16x8*)&lsrc[(size_t)(s0 + lr) * 3072 + lc];
#pragma unroll
    for (int j = 0; j < 8; ++j) ldst[j] = bf2f(v8[j]);
    __syncthreads();
#pragma unroll 4
    for (int sl = 0; sl < 16; ++sl) {
      const f32x4 kv4 = *(const f32x4*)&sK[sl][dg];
      const f32x4 vv4 = *(const f32x4*)&sV[sl][eg];
      acc0 += kv4[0] * vv4;
      acc1 += kv4[1] * vv4;
      acc2 += kv4[2] * vv4;
      acc3 += kv4[3] * vv4;
      ak4 += kv4;
    }
    __syncthreads();
  }
  float* outp = pkv + ((size_t)chunk * 64 + bh) * 4096;
  *(f32x4*)&outp[(dg + 0) * 64 + eg] = acc0;
  *(f32x4*)&outp[(dg + 1) * 64 + eg] = acc1;
  *(f32x4*)&outp[(dg + 2) * 64 + eg] = acc2;
  *(f32x4*)&outp[(dg + 3) * 64 + eg] = acc3;
  if (t < 16) *(f32x4*)&pks[((size_t)chunk * 64 + bh) * 64 + dg] = ak4;
}

// ---------------- reduce partials, fold division, emit bf16 ---------------
__global__ __launch_bounds__(256)
void kv_reduce_kernel(const float* __restrict__ pkv, const float* __restrict__ pks,
                      u16* __restrict__ kvnb) {
  const int bh = blockIdx.x;
  const int t = threadIdx.x;
  __shared__ float sks[64];
  if (t < 64) {
    float s = 0.f;
    for (int c = 0; c < 8; ++c) s += pks[((size_t)c * 64 + bh) * 64 + t];
    sks[t] = s + 1e-6f;
  }
  __syncthreads();
#pragma unroll
  for (int j = 0; j < 16; ++j) {
    int idx = t + j * 256;
    float s = 0.f;
    for (int c = 0; c < 8; ++c) s += pkv[((size_t)c * 64 + bh) * 4096 + idx];
    kvnb[(size_t)bh * 4096 + idx] = f2bf(s / sks[idx & 63]);
  }
}

// ---------------- W2T[b][j][h*64+d] = sum_e wo[j][h*64+e] * kvn[bh][d][e] --
// Folds kvn into w_out: out-projection becomes a plain GEMM vs q'.
// grid (64 bh, 4 jt); block 256 (4 waves x 64 j-rows). 32 MFMA/wave, K=64.
__global__ __launch_bounds__(256)
void w2t_kernel(const u16* __restrict__ wob, const u16* __restrict__ kvnb,
                u16* __restrict__ w2t) {
  const int bh = blockIdx.x;
  const int b = bh >> 4, h = bh & 15;
  const int wave = threadIdx.x >> 6, lane = threadIdx.x & 63;
  const int fr = lane & 15, fq = lane >> 4;
  const int j0 = blockIdx.y * 256 + wave * 64;
  __shared__ u16 sW[4][16 * 72];
  const u16* kvp = kvnb + (size_t)bh * 4096;
  bf16x8 bfr[4][2];
#pragma unroll
  for (int ks = 0; ks < 2; ++ks)
#pragma unroll
    for (int nn = 0; nn < 4; ++nn)
      bfr[nn][ks] = *(const bf16x8*)&kvp[(nn * 16 + fr) * 64 + ks * 32 + fq * 8];
  f32x4 acc[4][4] = {};
#pragma unroll
  for (int mm = 0; mm < 4; ++mm)
#pragma unroll
    for (int ks = 0; ks < 2; ++ks) {
      bf16x8 af = *(const bf16x8*)&wob[(size_t)(j0 + mm * 16 + fr) * 1024 + h * 64 + ks * 32 + fq * 8];
#pragma unroll
      for (int nn = 0; nn < 4; ++nn)
        acc[mm][nn] = __builtin_amdgcn_mfma_f32_16x16x32_bf16(af, bfr[nn][ks], acc[mm][nn], 0, 0, 0);
    }
  u16* wb = &sW[wave][0];
  u16* op = w2t + (size_t)b * 1048576 + h * 64;
  const int lrow = lane >> 3, lcol = (lane & 7) * 8;
#pragma unroll
  for (int mm = 0; mm < 4; ++mm) {
#pragma unroll
    for (int nn = 0; nn < 4; ++nn)
#pragma unroll
      for (int r = 0; r < 4; ++r)
        wb[(fq * 4 + r) * 72 + nn * 16 + fr] = f2bf(acc[mm][nn][r]);
#pragma unroll
    for (int i = 0; i < 2; ++i) {
      bf16x8 val = *(const bf16x8*)&wb[(i * 8 + lrow) * 72 + lcol];
      *(bf16x8*)&op[(size_t)(j0 + mm * 16 + i * 8 + lrow) * 1024 + lcol] = val;
    }
  }
}

// -------------------------------------------------------------------------
extern "C" void kernel_launch(void* const* d_in, const int* in_sizes, int n_in,
                              void* d_out, int out_size, void* d_ws, size_t ws_size,
                              hipStream_t stream) {
  const float* x     = (const float*)d_in[0];
  const float* w_qkv = (const float*)d_in[1];
  const float* b_qkv = (const float*)d_in[2];
  const float* w_out = (const float*)d_in[3];
  const float* b_out = (const float*)d_in[4];
  float* out = (float*)d_out;

  const int M = 16384, Dm = 1024, N3 = 3072;

  char* ws = (char*)d_ws;
  u16* xb     = (u16*)(ws);                    //  33,554,432 B
  u16* wqb    = (u16*)(ws + 33554432);         //   6,291,456 B
  u16* wob    = (u16*)(ws + 39845888);         //   2,097,152 B
  u16* qkvb   = (u16*)(ws + 41943040);         // 100,663,296 B
  u16* w2t    = (u16*)(ws + 142606336);        //   8,388,608 B (4 x 1024 x 1024 bf16)
  float* pkv  = (float*)(ws + 176160768);      //   8,388,608 B
  float* pks  = (float*)(ws + 184549376);      //     131,072 B
  u16* kvnb   = (u16*)(ws + 184680448);        //     524,288 B

  cvt_all_kernel<<<20480, 256, 0, stream>>>(x, xb, w_qkv, wqb, w_out, wob);

  // qkv projection + elu feature map
  gemm256<0><<<(M / 256) * (N3 / 256), 512, 0, stream>>>(
      xb, Dm, wqb, b_qkv, qkvb, N3, Dm, N3 / 256, 0);
  // kv state + normalization
  kv_state_kernel<<<dim3(64, 8), 256, 0, stream>>>(qkvb, pkv, pks);
  kv_reduce_kernel<<<64, 256, 0, stream>>>(pkv, pks, kvnb);
  // fold kvn into w_out (per b,h)
  w2t_kernel<<<dim3(64, 4), 256, 0, stream>>>(wob, kvnb, w2t);
  // out = q' @ W2T^T + b_out   (A = qkvb cols 0..1023, lda=3072; B per batch)
  gemm256<1><<<(M / 256) * (Dm / 256), 512, 0, stream>>>(
      qkvb, N3, w2t, b_out, out, Dm, Dm, Dm / 256, 1 << 20);
}